// Round 1
// baseline (398.418 us; speedup 1.0000x reference)
//
#include <hip/hip_runtime.h>

typedef unsigned short u16;
typedef __attribute__((ext_vector_type(8))) short bf16x8;
typedef __attribute__((ext_vector_type(4))) float f32x4;

__device__ __forceinline__ u16 f2bf(float f) {
  unsigned u = __float_as_uint(f);
  u = u + 0x7fffu + ((u >> 16) & 1u);   // round-to-nearest-even (inputs finite)
  return (u16)(u >> 16);
}
__device__ __forceinline__ float bf2f(u16 h) {
  return __uint_as_float(((unsigned)h) << 16);
}

// ---------------- fp32 -> bf16 convert (vectorized) ----------------
__global__ __launch_bounds__(256) void cvt_f32_bf16(const float* __restrict__ in,
                                                    u16* __restrict__ out, int n4) {
  int i = blockIdx.x * 256 + threadIdx.x;
  if (i < n4) {
    float4 v = reinterpret_cast<const float4*>(in)[i];
    ushort4 o = make_ushort4(f2bf(v.x), f2bf(v.y), f2bf(v.z), f2bf(v.w));
    reinterpret_cast<ushort4*>(out)[i] = o;
  }
}

// ------------- transpose + convert: in[R][C] f32 -> out[C][R] bf16 -------------
__global__ __launch_bounds__(256) void transpose_cvt(const float* __restrict__ in,
                                                     u16* __restrict__ out, int R, int C) {
  __shared__ float tile[32][33];
  int tx = threadIdx.x & 31, ty = threadIdx.x >> 5;  // 32 x 8
  int c0 = blockIdx.x * 32, r0 = blockIdx.y * 32;
#pragma unroll
  for (int i = 0; i < 32; i += 8)
    tile[ty + i][tx] = in[(size_t)(r0 + ty + i) * C + c0 + tx];
  __syncthreads();
#pragma unroll
  for (int i = 0; i < 32; i += 8)
    out[(size_t)(c0 + ty + i) * R + r0 + tx] = f2bf(tile[tx][ty + i]);
}

// ---------------- RoPE cos/sin table: [2048][32] ----------------
__global__ __launch_bounds__(256) void rope_table(float* __restrict__ cost,
                                                  float* __restrict__ sint) {
  int idx = blockIdx.x * 256 + threadIdx.x;  // 65536
  int i = idx & 31, t = idx >> 5;
  float invf = powf(10000.0f, -(float)(2 * i) / 64.0f);
  float f = (float)t * invf;
  cost[idx] = cosf(f);
  sint[idx] = sinf(f);
}

// ---------------- RoPE apply (in-place on q_ws, k_ws; bf16) ----------------
__global__ __launch_bounds__(256) void rope_apply(u16* __restrict__ q_ws, u16* __restrict__ k_ws,
                                                  const float* __restrict__ cost,
                                                  const float* __restrict__ sint) {
  int idx = blockIdx.x * 256 + threadIdx.x;  // 2^22: [which][bh][t][pair]
  int i = idx & 31;
  int t = (idx >> 5) & 2047;
  int bh = (idx >> 16) & 31;
  int which = idx >> 21;
  u16* p = which ? k_ws : q_ws;
  size_t off = ((size_t)bh * 2048 + t) * 64 + 2 * i;
  float c = cost[(t << 5) + i], s = sint[(t << 5) + i];
  float x1 = bf2f(p[off]), x2 = bf2f(p[off + 1]);
  p[off]     = f2bf(x1 * c - x2 * s);
  p[off + 1] = f2bf(x2 * c + x1 * s);
}

// ---------------- bf16 GEMM: C[M][N] = A[M][K] @ Bt[N][K]^T + bias ----------------
// mode 0: write fp32 to Cf.  mode 1: scatter bf16 q/k/v as [b][h][t][64].
#define BM 128
#define BN 128
#define BKK 32
__global__ __launch_bounds__(256) void gemm_bt(
    const u16* __restrict__ A, const u16* __restrict__ Bt, const float* __restrict__ bias,
    float* __restrict__ Cf, u16* __restrict__ q_ws, u16* __restrict__ k_ws, u16* __restrict__ v_ws,
    int M, int N, int K, int mode) {
  __shared__ u16 As[BM][BKK];
  __shared__ u16 Bs[BN][BKK];
  const int tid = threadIdx.x;
  const int lane = tid & 63;
  const int wid = tid >> 6;
  const int wr = wid >> 1, wc = wid & 1;       // 2x2 waves, 64x64 each
  const int fr = lane & 15, fg = lane >> 4;
  const int m0 = blockIdx.y * BM, n0 = blockIdx.x * BN;

  const int srow = tid >> 1;
  const int scol = (tid & 1) * 16;
  const uint4* gA = reinterpret_cast<const uint4*>(A + (size_t)(m0 + srow) * K + scol);
  const uint4* gB = reinterpret_cast<const uint4*>(Bt + (size_t)(n0 + srow) * K + scol);

  f32x4 acc[4][4] = {};

  for (int k0 = 0; k0 < K; k0 += BKK) {
    uint4 a0 = gA[k0 >> 3], a1 = gA[(k0 >> 3) + 1];
    uint4 b0 = gB[k0 >> 3], b1 = gB[(k0 >> 3) + 1];
    *reinterpret_cast<uint4*>(&As[srow][scol]) = a0;
    *reinterpret_cast<uint4*>(&As[srow][scol + 8]) = a1;
    *reinterpret_cast<uint4*>(&Bs[srow][scol]) = b0;
    *reinterpret_cast<uint4*>(&Bs[srow][scol + 8]) = b1;
    __syncthreads();
    bf16x8 af[4], bfr[4];
#pragma unroll
    for (int i = 0; i < 4; i++)
      af[i] = *reinterpret_cast<const bf16x8*>(&As[wr * 64 + i * 16 + fr][fg * 8]);
#pragma unroll
    for (int j = 0; j < 4; j++)
      bfr[j] = *reinterpret_cast<const bf16x8*>(&Bs[wc * 64 + j * 16 + fr][fg * 8]);
#pragma unroll
    for (int i = 0; i < 4; i++)
#pragma unroll
      for (int j = 0; j < 4; j++)
        acc[i][j] = __builtin_amdgcn_mfma_f32_16x16x32_bf16(af[i], bfr[j], acc[i][j], 0, 0, 0);
    __syncthreads();
  }

  // C/D layout (HW-verified): col = lane&15, row = (lane>>4)*4 + reg
#pragma unroll
  for (int i = 0; i < 4; i++) {
    int rowb = m0 + wr * 64 + i * 16 + fg * 4;
#pragma unroll
    for (int j = 0; j < 4; j++) {
      int col = n0 + wc * 64 + j * 16 + fr;
      float bv = bias[col];
#pragma unroll
      for (int r = 0; r < 4; r++) {
        float v = acc[i][j][r] + bv;
        int rr = rowb + r;
        if (mode == 0) {
          Cf[(size_t)rr * N + col] = v;
        } else {
          int b = rr >> 11, t = rr & 2047;
          int sec = col >> 10, nn = col & 1023;
          int h = nn >> 6, d = nn & 63;
          size_t dst = ((size_t)((b << 4) + h) * 2048 + t) * 64 + d;
          u16 val = f2bf(v);
          if (sec == 0) q_ws[dst] = val;
          else if (sec == 1) k_ws[dst] = val;
          else v_ws[dst] = val;
        }
      }
    }
  }
}

// ---------------- flash attention: per (qtile of 64 rows, bh) ----------------
__global__ __launch_bounds__(256) void attn_fwd(const u16* __restrict__ q_ws,
                                                const u16* __restrict__ k_ws,
                                                const u16* __restrict__ v_ws,
                                                u16* __restrict__ attn_out) {
  const int tid = threadIdx.x, lane = tid & 63, wid = tid >> 6;
  const int fr = lane & 15, fg = lane >> 4;
  const int qt = blockIdx.x, bh = blockIdx.y;
  const size_t base = (size_t)bh * (2048 * 64);
  const int q0 = qt * 64 + wid * 16;  // this wave's 16 q rows

  __shared__ u16 Vt[64][32];          // V tile transposed: [d][key]
  __shared__ float Pl[4][16][32];     // per-wave P (q-row major)

  bf16x8 qf0 = *reinterpret_cast<const bf16x8*>(q_ws + base + (size_t)(q0 + fr) * 64 + fg * 8);
  bf16x8 qf1 = *reinterpret_cast<const bf16x8*>(q_ws + base + (size_t)(q0 + fr) * 64 + 32 + fg * 8);

  float m_i[4], l_i[4];
  f32x4 of[4] = {};
#pragma unroll
  for (int r = 0; r < 4; r++) { m_i[r] = -1e30f; l_i[r] = 0.f; }

  for (int kv = 0; kv < 2048; kv += 32) {
    {  // stage Vt (transpose via LDS)
      int key = tid >> 3, d0 = (tid & 7) * 8;
      bf16x8 vv = *reinterpret_cast<const bf16x8*>(v_ws + base + (size_t)(kv + key) * 64 + d0);
#pragma unroll
      for (int j = 0; j < 8; j++) Vt[d0 + j][key] = (u16)vv[j];
    }
    __syncthreads();

    // S = Q @ K^T : two 16-key blocks, feat contracted 2x32
    f32x4 s0 = {0.f, 0.f, 0.f, 0.f}, s1 = {0.f, 0.f, 0.f, 0.f};
    {
      const u16* kbase = k_ws + base + (size_t)kv * 64;
      bf16x8 kf0a = *reinterpret_cast<const bf16x8*>(kbase + (size_t)fr * 64 + fg * 8);
      bf16x8 kf0b = *reinterpret_cast<const bf16x8*>(kbase + (size_t)fr * 64 + 32 + fg * 8);
      s0 = __builtin_amdgcn_mfma_f32_16x16x32_bf16(qf0, kf0a, s0, 0, 0, 0);
      s0 = __builtin_amdgcn_mfma_f32_16x16x32_bf16(qf1, kf0b, s0, 0, 0, 0);
      bf16x8 kf1a = *reinterpret_cast<const bf16x8*>(kbase + (size_t)(16 + fr) * 64 + fg * 8);
      bf16x8 kf1b = *reinterpret_cast<const bf16x8*>(kbase + (size_t)(16 + fr) * 64 + 32 + fg * 8);
      s1 = __builtin_amdgcn_mfma_f32_16x16x32_bf16(qf0, kf1a, s1, 0, 0, 0);
      s1 = __builtin_amdgcn_mfma_f32_16x16x32_bf16(qf1, kf1b, s1, 0, 0, 0);
    }

    // online softmax (rows = fg*4 + r; 16-lane groups hold the key axis)
#pragma unroll
    for (int r = 0; r < 4; r++) {
      float a = s0[r] * 0.125f, b = s1[r] * 0.125f;
      float mx = fmaxf(a, b);
      mx = fmaxf(mx, __shfl_xor(mx, 1));
      mx = fmaxf(mx, __shfl_xor(mx, 2));
      mx = fmaxf(mx, __shfl_xor(mx, 4));
      mx = fmaxf(mx, __shfl_xor(mx, 8));
      float mn = fmaxf(m_i[r], mx);
      float alpha = __expf(m_i[r] - mn);
      m_i[r] = mn;
      float p0 = __expf(a - mn), p1 = __expf(b - mn);
      float rs = p0 + p1;
      rs += __shfl_xor(rs, 1);
      rs += __shfl_xor(rs, 2);
      rs += __shfl_xor(rs, 4);
      rs += __shfl_xor(rs, 8);
      l_i[r] = l_i[r] * alpha + rs;
      int prow = fg * 4 + r;
      Pl[wid][prow][fr] = p0;
      Pl[wid][prow][16 + fr] = p1;
#pragma unroll
      for (int j = 0; j < 4; j++) of[j][r] *= alpha;
    }
    __syncthreads();  // Pl transpose visible; Vt still valid

    // PV: A = P[q][key] (bf16), B = V[key][d] via Vt
    bf16x8 pf;
    {
      const float* prow = &Pl[wid][fr][fg * 8];
#pragma unroll
      for (int i = 0; i < 8; i++) pf[i] = (short)f2bf(prow[i]);
    }
#pragma unroll
    for (int j = 0; j < 4; j++) {
      bf16x8 vf = *reinterpret_cast<const bf16x8*>(&Vt[j * 16 + fr][fg * 8]);
      of[j] = __builtin_amdgcn_mfma_f32_16x16x32_bf16(pf, vf, of[j], 0, 0, 0);
    }
    __syncthreads();  // done with Vt before restage
  }

  const int b = bh >> 4, h = bh & 15;
#pragma unroll
  for (int j = 0; j < 4; j++) {
#pragma unroll
    for (int r = 0; r < 4; r++) {
      int t = q0 + fg * 4 + r;
      float o = of[j][r] / l_i[r];
      attn_out[((size_t)(b * 2048 + t)) * 1024 + h * 64 + j * 16 + fr] = f2bf(o);
    }
  }
}

extern "C" void kernel_launch(void* const* d_in, const int* in_sizes, int n_in,
                              void* d_out, int out_size, void* d_ws, size_t ws_size,
                              hipStream_t stream) {
  const float* x     = (const float*)d_in[0];  // [2][2048][1024]
  const float* w_qkv = (const float*)d_in[1];  // [1024][3072]
  const float* b_qkv = (const float*)d_in[2];  // [3072]
  const float* w_out = (const float*)d_in[3];  // [1024][1024]
  const float* b_out = (const float*)d_in[4];  // [1024]
  float* out = (float*)d_out;                  // [2][2048][1024] fp32

  char* ws = (char*)d_ws;
  const size_t MB = 1024 * 1024;
  u16*   x_bf   = (u16*)(ws);                       // 8 MB  [4096][1024]
  u16*   wqkvT  = (u16*)(ws + 8 * MB);              // 6 MB  [3072][1024]
  u16*   woutT  = (u16*)(ws + 14 * MB);             // 2 MB  [1024][1024]
  u16*   q_ws   = (u16*)(ws + 16 * MB);             // 8 MB  [2][16][2048][64]
  u16*   k_ws   = (u16*)(ws + 24 * MB);             // 8 MB
  u16*   v_ws   = (u16*)(ws + 32 * MB);             // 8 MB
  u16*   attn_o = (u16*)(ws + 40 * MB);             // 8 MB  [4096][1024]
  float* cost   = (float*)(ws + 48 * MB);           // 256 KB [2048][32]
  float* sint   = (float*)(ws + 48 * MB + 256 * 1024);

  cvt_f32_bf16<<<4096, 256, 0, stream>>>(x, x_bf, 1048576);
  transpose_cvt<<<dim3(96, 32), 256, 0, stream>>>(w_qkv, wqkvT, 1024, 3072);
  transpose_cvt<<<dim3(32, 32), 256, 0, stream>>>(w_out, woutT, 1024, 1024);
  rope_table<<<256, 256, 0, stream>>>(cost, sint);
  gemm_bt<<<dim3(24, 32), 256, 0, stream>>>(x_bf, wqkvT, b_qkv, nullptr, q_ws, k_ws, v_ws,
                                            4096, 3072, 1024, 1);
  rope_apply<<<16384, 256, 0, stream>>>(q_ws, k_ws, cost, sint);
  attn_fwd<<<dim3(32, 32), 256, 0, stream>>>(q_ws, k_ws, v_ws, attn_o);
  gemm_bt<<<dim3(8, 32), 256, 0, stream>>>(attn_o, woutT, b_out, out, nullptr, nullptr, nullptr,
                                           4096, 1024, 1024, 0);
}

// Round 2
// 274.382 us; speedup vs baseline: 1.4521x; 1.4521x over previous
//
#include <hip/hip_runtime.h>

typedef unsigned short u16;
typedef unsigned int u32;
typedef __attribute__((ext_vector_type(8))) short bf16x8;
typedef __attribute__((ext_vector_type(4))) float f32x4;
typedef __attribute__((ext_vector_type(16))) float f32x16;

typedef __attribute__((address_space(1))) const u32* gas_ptr;
typedef __attribute__((address_space(3))) u32* las_ptr;

__device__ __forceinline__ void gld16(const void* g, void* l) {
  // async global->LDS, 16B per lane; LDS dest = wave-uniform base + lane*16
  __builtin_amdgcn_global_load_lds((gas_ptr)g, (las_ptr)l, 16, 0, 0);
}

__device__ __forceinline__ u16 f2bf(float f) {
  unsigned u = __float_as_uint(f);
  u = u + 0x7fffu + ((u >> 16) & 1u);   // RNE (inputs finite)
  return (u16)(u >> 16);
}
__device__ __forceinline__ float bf2f(u16 h) {
  return __uint_as_float(((unsigned)h) << 16);
}

// ---------------- fp32 -> bf16 convert (vectorized) ----------------
__global__ __launch_bounds__(256) void cvt_f32_bf16(const float* __restrict__ in,
                                                    u16* __restrict__ out, int n4) {
  int i = blockIdx.x * 256 + threadIdx.x;
  if (i < n4) {
    float4 v = reinterpret_cast<const float4*>(in)[i];
    ushort4 o = make_ushort4(f2bf(v.x), f2bf(v.y), f2bf(v.z), f2bf(v.w));
    reinterpret_cast<ushort4*>(out)[i] = o;
  }
}

// ------------- transpose + convert: in[R][C] f32 -> out[C][R] bf16 -------------
__global__ __launch_bounds__(256) void transpose_cvt(const float* __restrict__ in,
                                                     u16* __restrict__ out, int R, int C) {
  __shared__ float tile[32][33];
  int tx = threadIdx.x & 31, ty = threadIdx.x >> 5;  // 32 x 8
  int c0 = blockIdx.x * 32, r0 = blockIdx.y * 32;
#pragma unroll
  for (int i = 0; i < 32; i += 8)
    tile[ty + i][tx] = in[(size_t)(r0 + ty + i) * C + c0 + tx];
  __syncthreads();
#pragma unroll
  for (int i = 0; i < 32; i += 8)
    out[(size_t)(c0 + ty + i) * R + r0 + tx] = f2bf(tile[tx][ty + i]);
}

// ---------------- RoPE cos/sin table: [2048][32] ----------------
__global__ __launch_bounds__(256) void rope_table(float* __restrict__ cost,
                                                  float* __restrict__ sint) {
  int idx = blockIdx.x * 256 + threadIdx.x;  // 65536
  int i = idx & 31, t = idx >> 5;
  float invf = powf(10000.0f, -(float)(2 * i) / 64.0f);
  float f = (float)t * invf;
  cost[idx] = cosf(f);
  sint[idx] = sinf(f);
}

// ---------------- RoPE apply (in-place on q_ws, k_ws; bf16) ----------------
__global__ __launch_bounds__(256) void rope_apply(u16* __restrict__ q_ws, u16* __restrict__ k_ws,
                                                  const float* __restrict__ cost,
                                                  const float* __restrict__ sint) {
  int idx = blockIdx.x * 256 + threadIdx.x;  // 2^22: [which][bh][t][pair]
  int i = idx & 31;
  int t = (idx >> 5) & 2047;
  int bh = (idx >> 16) & 31;
  int which = idx >> 21;
  u16* p = which ? k_ws : q_ws;
  size_t off = ((size_t)bh * 2048 + t) * 64 + 2 * i;
  float c = cost[(t << 5) + i], s = sint[(t << 5) + i];
  float x1 = bf2f(p[off]), x2 = bf2f(p[off + 1]);
  p[off]     = f2bf(x1 * c - x2 * s);
  p[off + 1] = f2bf(x2 * c + x1 * s);
}

// ---------------- bf16 GEMM: C[M][N] = A[M][K] @ Bt[N][K]^T + bias ----------------
// Staging via global_load_lds width=16 (m97 recipe).
#define BM 128
#define BN 128
#define BKK 32
__global__ __launch_bounds__(256) void gemm_bt(
    const u16* __restrict__ A, const u16* __restrict__ Bt, const float* __restrict__ bias,
    float* __restrict__ Cf, u16* __restrict__ q_ws, u16* __restrict__ k_ws, u16* __restrict__ v_ws,
    int M, int N, int K, int mode) {
  __shared__ u16 As[BM][BKK];
  __shared__ u16 Bs[BN][BKK];
  const int tid = threadIdx.x;
  const int lane = tid & 63;
  const int wid = tid >> 6;
  const int wr = wid >> 1, wc = wid & 1;       // 2x2 waves, 64x64 each
  const int fr = lane & 15, fg = lane >> 4;
  const int m0 = blockIdx.y * BM, n0 = blockIdx.x * BN;

  const int row_l = lane >> 2;      // 0..15 (per gld instr, 16 rows)
  const int slot_l = lane & 3;      // 4 x 8 u16 = 64B row

  f32x4 acc[4][4] = {};

  for (int k0 = 0; k0 < K; k0 += BKK) {
#pragma unroll
    for (int i = 0; i < 2; i++) {
      int rowA = wid * 32 + i * 16;
      gld16(A  + (size_t)(m0 + rowA + row_l) * K + k0 + slot_l * 8, &As[rowA][0]);
      gld16(Bt + (size_t)(n0 + rowA + row_l) * K + k0 + slot_l * 8, &Bs[rowA][0]);
    }
    __syncthreads();
    bf16x8 af[4], bfr[4];
#pragma unroll
    for (int i = 0; i < 4; i++)
      af[i] = *reinterpret_cast<const bf16x8*>(&As[wr * 64 + i * 16 + fr][fg * 8]);
#pragma unroll
    for (int j = 0; j < 4; j++)
      bfr[j] = *reinterpret_cast<const bf16x8*>(&Bs[wc * 64 + j * 16 + fr][fg * 8]);
#pragma unroll
    for (int i = 0; i < 4; i++)
#pragma unroll
      for (int j = 0; j < 4; j++)
        acc[i][j] = __builtin_amdgcn_mfma_f32_16x16x32_bf16(af[i], bfr[j], acc[i][j], 0, 0, 0);
    __syncthreads();
  }

  // C/D layout (HW-verified): col = lane&15, row = (lane>>4)*4 + reg
#pragma unroll
  for (int i = 0; i < 4; i++) {
    int rowb = m0 + wr * 64 + i * 16 + fg * 4;
#pragma unroll
    for (int j = 0; j < 4; j++) {
      int col = n0 + wc * 64 + j * 16 + fr;
      float bv = bias[col];
#pragma unroll
      for (int r = 0; r < 4; r++) {
        float v = acc[i][j][r] + bv;
        int rr = rowb + r;
        if (mode == 0) {
          Cf[(size_t)rr * N + col] = v;
        } else {
          int b = rr >> 11, t = rr & 2047;
          int sec = col >> 10, nn = col & 1023;
          int h = nn >> 6, d = nn & 63;
          size_t dst = ((size_t)((b << 4) + h) * 2048 + t) * 64 + d;
          u16 val = f2bf(v);
          if (sec == 0) q_ws[dst] = val;
          else if (sec == 1) k_ws[dst] = val;
          else v_ws[dst] = val;
        }
      }
    }
  }
}

// ---------------- flash attention, 32x32 MFMA, swapped-operand dataflow ----------------
// Per block: 4 waves x 64 q-rows = 256 q. KVBLK=64, double-buffered K/V in LDS.
// S^T = K @ Q^T  (A=K frags from swizzled LDS, B=Q in regs) -> lane holds one q (col=lane&31).
// O^T = V^T @ P^T (A=V^T frags from swizzled LDS, B=P packed from own S regs; k-permuted
// consistently on both operands so no cross-lane P movement is needed).
#define KVB 64
#define NT 32
#define CSC 0.18033688011112042f   /* log2(e)/8 */

__global__ __launch_bounds__(256, 1) void attn_fwd(const u16* __restrict__ q_ws,
                                                   const u16* __restrict__ k_ws,
                                                   const u16* __restrict__ v_ws,
                                                   u16* __restrict__ attn_out) {
  __shared__ u16 Klds[2][4096];  // byte(row,d)  = row*128 + (d*2  ^ ((row&7)<<4))
  __shared__ u16 Vlds[2][4096];  // byte(d,key)  = d*128   + (key*2 ^ ((d&7)<<4))

  const int tid = threadIdx.x, lane = tid & 63, w = tid >> 6;
  const int l31 = lane & 31, hi = lane >> 5;
  const int bh = blockIdx.y;
  const size_t base = (size_t)bh * (2048 * 64);
  const int q0 = blockIdx.x * 256 + w * 64;

  // ---- Q fragments in registers: qf[qsub][dblk], d = dblk*16 + hi*8 + j ----
  bf16x8 qf[2][4];
#pragma unroll
  for (int qs = 0; qs < 2; qs++)
#pragma unroll
    for (int db = 0; db < 4; db++)
      qf[qs][db] = *reinterpret_cast<const bf16x8*>(
          q_ws + base + (size_t)(q0 + qs * 32 + l31) * 64 + db * 16 + hi * 8);

  f32x16 Oa[2][2] = {};          // [qsub][dsub], O^T: col=q(lane&31), row=d
  float m_i[2] = {-1e30f, -1e30f}, l_i[2] = {0.f, 0.f};

  const int krow_l = lane >> 3, kslot_l = lane & 7;
  const int vkey = tid & 31, vc = tid >> 5;
  const u16* kg = k_ws + base;
  const u16* vg = v_ws + base;

  // ---- staging lambdas (macros for clarity) ----
#define STAGE_K(kv, buf)                                                          \
  {                                                                               \
    _Pragma("unroll") for (int i = 0; i < 2; i++) {                               \
      int row = w * 16 + i * 8 + krow_l;                                          \
      int srcslot = kslot_l ^ (row & 7);                                          \
      gld16(kg + (size_t)((kv) + row) * 64 + srcslot * 8, &Klds[buf][(w * 16 + i * 8) * 64]); \
    }                                                                             \
  }
#define LOAD_V(kv, vr)                                                            \
  {                                                                               \
    vr[0] = *reinterpret_cast<const uint4*>(vg + (size_t)((kv) + vkey) * 64 + vc * 8);        \
    vr[1] = *reinterpret_cast<const uint4*>(vg + (size_t)((kv) + vkey + 32) * 64 + vc * 8);   \
  }
#define SCATTER_V(vr, buf)                                                        \
  {                                                                               \
    _Pragma("unroll") for (int it = 0; it < 2; it++) {                            \
      const u16* pe = (const u16*)&vr[it];                                        \
      int key2 = (vkey + 32 * it) * 2;                                            \
      _Pragma("unroll") for (int j = 0; j < 8; j++) {                             \
        int byte = (vc * 8 + j) * 128 + (key2 ^ (j << 4));                        \
        *(u16*)((char*)&Vlds[buf][0] + byte) = pe[j];                             \
      }                                                                           \
    }                                                                             \
  }

  uint4 vr[2];
  STAGE_K(0, 0);
  LOAD_V(0, vr);
  __syncthreads();
  SCATTER_V(vr, 0);
  __syncthreads();

  int cur = 0;
  for (int t = 0; t < NT; t++) {
    if (t + 1 < NT) {
      STAGE_K((t + 1) * KVB, cur ^ 1);
      LOAD_V((t + 1) * KVB, vr);
    }

    const char* Kb = (const char*)&Klds[cur][0];
    const char* Vb = (const char*)&Vlds[cur][0];

    // K fragments: kf[ksub][dblk], key = ksub*32 + (lane&31), d = dblk*16 + hi*8 + j
    bf16x8 kf[2][4];
#pragma unroll
    for (int ks = 0; ks < 2; ks++) {
      int krow = (l31 + 32 * ks) * 128;
      int ksw = (l31 & 7) << 4;
#pragma unroll
      for (int db = 0; db < 4; db++)
        kf[ks][db] = *reinterpret_cast<const bf16x8*>(Kb + krow + ((db * 32 + hi * 16) ^ ksw));
    }

#pragma unroll
    for (int qs = 0; qs < 2; qs++) {
      f32x16 s0 = {}, s1 = {};
#pragma unroll
      for (int db = 0; db < 4; db++) {
        s0 = __builtin_amdgcn_mfma_f32_32x32x16_bf16(kf[0][db], qf[qs][db], s0, 0, 0, 0);
        s1 = __builtin_amdgcn_mfma_f32_32x32x16_bf16(kf[1][db], qf[qs][db], s1, 0, 0, 0);
      }
      // ---- online softmax, fully lane-local (one q per lane, 32 keys split with lane^32) ----
      float p[32];
#pragma unroll
      for (int i = 0; i < 16; i++) { p[i] = s0[i] * CSC; p[16 + i] = s1[i] * CSC; }
      float zmax = -1e30f;
#pragma unroll
      for (int i = 0; i < 32; i++) zmax = fmaxf(zmax, p[i]);
      zmax = fmaxf(zmax, __shfl_xor(zmax, 32));
      float mn = fmaxf(m_i[qs], zmax);
      float alpha = exp2f(m_i[qs] - mn);
      m_i[qs] = mn;
      float rs = 0.f;
#pragma unroll
      for (int i = 0; i < 32; i++) { p[i] = exp2f(p[i] - mn); rs += p[i]; }
      rs += __shfl_xor(rs, 32);
      l_i[qs] = l_i[qs] * alpha + rs;
#pragma unroll
      for (int ds = 0; ds < 2; ds++)
#pragma unroll
        for (int r = 0; r < 16; r++) Oa[qs][ds][r] *= alpha;

      // pack P -> bf16 words; pw[ksub*8+w] = keys crow(2w,hi), crow(2w+1,hi) (+32*ksub)
      u32 pw[16];
#pragma unroll
      for (int kk = 0; kk < 2; kk++)
#pragma unroll
        for (int wd = 0; wd < 8; wd++)
          pw[kk * 8 + wd] =
              ((u32)f2bf(p[kk * 16 + 2 * wd + 1]) << 16) | (u32)f2bf(p[kk * 16 + 2 * wd]);

      // ---- PV: O^T += V^T @ P^T ----
      int vsw = (l31 & 7) << 4;
#pragma unroll
      for (int ds = 0; ds < 2; ds++) {
        int vrow = (l31 + 32 * ds) * 128;
#pragma unroll
        for (int kb = 0; kb < 4; kb++) {
          uint2 va = *(const uint2*)(Vb + vrow + ((kb * 32 + hi * 8) ^ vsw));
          uint2 vb = *(const uint2*)(Vb + vrow + ((kb * 32 + hi * 8 + 16) ^ vsw));
          union { u32 u[4]; bf16x8 v; } vf, pf;
          vf.u[0] = va.x; vf.u[1] = va.y; vf.u[2] = vb.x; vf.u[3] = vb.y;
          int pb = (kb >> 1) * 8 + (kb & 1) * 4;
          pf.u[0] = pw[pb]; pf.u[1] = pw[pb + 1]; pf.u[2] = pw[pb + 2]; pf.u[3] = pw[pb + 3];
          Oa[qs][ds] = __builtin_amdgcn_mfma_f32_32x32x16_bf16(vf.v, pf.v, Oa[qs][ds], 0, 0, 0);
        }
      }
    }

    __syncthreads();
    if (t + 1 < NT) SCATTER_V(vr, cur ^ 1);
    __syncthreads();
    cur ^= 1;
  }

  // ---- epilogue: O^T regs -> global [b][t][h*64+d], row=d=crow(reg,hi)+32*ds, col=q ----
  const int b = bh >> 4, h = bh & 15;
#pragma unroll
  for (int qs = 0; qs < 2; qs++) {
    float invl = 1.0f / l_i[qs];
    int row = q0 + qs * 32 + l31;
    size_t rbase = ((size_t)(b * 2048 + row)) * 1024 + h * 64;
#pragma unroll
    for (int ds = 0; ds < 2; ds++)
#pragma unroll
      for (int rg = 0; rg < 4; rg++) {
        int d0 = rg * 8 + hi * 4 + ds * 32;
        ushort4 st;
        st.x = f2bf(Oa[qs][ds][rg * 4 + 0] * invl);
        st.y = f2bf(Oa[qs][ds][rg * 4 + 1] * invl);
        st.z = f2bf(Oa[qs][ds][rg * 4 + 2] * invl);
        st.w = f2bf(Oa[qs][ds][rg * 4 + 3] * invl);
        *reinterpret_cast<ushort4*>(attn_out + rbase + d0) = st;
      }
  }
#undef STAGE_K
#undef LOAD_V
#undef SCATTER_V
}

extern "C" void kernel_launch(void* const* d_in, const int* in_sizes, int n_in,
                              void* d_out, int out_size, void* d_ws, size_t ws_size,
                              hipStream_t stream) {
  const float* x     = (const float*)d_in[0];  // [2][2048][1024]
  const float* w_qkv = (const float*)d_in[1];  // [1024][3072]
  const float* b_qkv = (const float*)d_in[2];  // [3072]
  const float* w_out = (const float*)d_in[3];  // [1024][1024]
  const float* b_out = (const float*)d_in[4];  // [1024]
  float* out = (float*)d_out;                  // [2][2048][1024] fp32

  char* ws = (char*)d_ws;
  const size_t MB = 1024 * 1024;
  u16*   x_bf   = (u16*)(ws);                       // 8 MB  [4096][1024]
  u16*   wqkvT  = (u16*)(ws + 8 * MB);              // 6 MB  [3072][1024]
  u16*   woutT  = (u16*)(ws + 14 * MB);             // 2 MB  [1024][1024]
  u16*   q_ws   = (u16*)(ws + 16 * MB);             // 8 MB  [2][16][2048][64]
  u16*   k_ws   = (u16*)(ws + 24 * MB);             // 8 MB
  u16*   v_ws   = (u16*)(ws + 32 * MB);             // 8 MB
  u16*   attn_o = (u16*)(ws + 40 * MB);             // 8 MB  [4096][1024]
  float* cost   = (float*)(ws + 48 * MB);           // 256 KB [2048][32]
  float* sint   = (float*)(ws + 48 * MB + 256 * 1024);

  cvt_f32_bf16<<<4096, 256, 0, stream>>>(x, x_bf, 1048576);
  transpose_cvt<<<dim3(96, 32), 256, 0, stream>>>(w_qkv, wqkvT, 1024, 3072);
  transpose_cvt<<<dim3(32, 32), 256, 0, stream>>>(w_out, woutT, 1024, 1024);
  rope_table<<<256, 256, 0, stream>>>(cost, sint);
  gemm_bt<<<dim3(24, 32), 256, 0, stream>>>(x_bf, wqkvT, b_qkv, nullptr, q_ws, k_ws, v_ws,
                                            4096, 3072, 1024, 1);
  rope_apply<<<16384, 256, 0, stream>>>(q_ws, k_ws, cost, sint);
  attn_fwd<<<dim3(8, 32), 256, 0, stream>>>(q_ws, k_ws, v_ws, attn_o);
  gemm_bt<<<dim3(8, 32), 256, 0, stream>>>(attn_o, woutT, b_out, out, nullptr, nullptr, nullptr,
                                           4096, 1024, 1024, 0);
}

// Round 5
// 244.583 us; speedup vs baseline: 1.6290x; 1.1218x over previous
//
#include <hip/hip_runtime.h>

typedef unsigned short u16;
typedef unsigned int u32;
typedef __attribute__((ext_vector_type(8))) short bf16x8;
typedef __attribute__((ext_vector_type(4))) float f32x4;
typedef __attribute__((ext_vector_type(16))) float f32x16;

typedef __attribute__((address_space(1))) const u32* gas_ptr;
typedef __attribute__((address_space(3))) u32* las_ptr;

__device__ __forceinline__ void gld16(const void* g, void* l) {
  __builtin_amdgcn_global_load_lds((gas_ptr)g, (las_ptr)l, 16, 0, 0);
}

__device__ __forceinline__ u16 f2bf(float f) {
  unsigned u = __float_as_uint(f);
  u = u + 0x7fffu + ((u >> 16) & 1u);   // RNE (inputs finite)
  return (u16)(u >> 16);
}

// ---------------- fused prep: cvt x, transpose w_qkv/w_out, cos/sin table ----------------
__global__ __launch_bounds__(256) void prep(const float* __restrict__ x, u16* __restrict__ x_bf,
                                            const float* __restrict__ wqkv, u16* __restrict__ wqkvT,
                                            const float* __restrict__ wout, u16* __restrict__ woutT,
                                            float2* __restrict__ cs) {
  __shared__ float tile[32][33];
  const int b = blockIdx.x, tid = threadIdx.x;
  if (b < 4096) {                       // x: fp32 -> bf16, 4096*256*4 elems
    int i = b * 256 + tid;
    float4 v = reinterpret_cast<const float4*>(x)[i];
    ushort4 o = make_ushort4(f2bf(v.x), f2bf(v.y), f2bf(v.z), f2bf(v.w));
    reinterpret_cast<ushort4*>(x_bf)[i] = o;
  } else if (b < 8192) {                // transposes
    const float* in; u16* out; int R, C, bx, by;
    if (b < 7168) { in = wqkv; out = wqkvT; R = 1024; C = 3072; int b2 = b - 4096; bx = b2 % 96; by = b2 / 96; }
    else          { in = wout; out = woutT; R = 1024; C = 1024; int b3 = b - 7168; bx = b3 % 32; by = b3 / 32; }
    int tx = tid & 31, ty = tid >> 5;
    int c0 = bx * 32, r0 = by * 32;
#pragma unroll
    for (int i = 0; i < 32; i += 8)
      tile[ty + i][tx] = in[(size_t)(r0 + ty + i) * C + c0 + tx];
    __syncthreads();
#pragma unroll
    for (int i = 0; i < 32; i += 8)
      out[(size_t)(c0 + ty + i) * R + r0 + tx] = f2bf(tile[tx][ty + i]);
  } else {                              // cos/sin table [2048][32] float2
    int idx = (b - 8192) * 256 + tid;
    int i = idx & 31, t = idx >> 5;
    float invf = powf(10000.0f, -(float)(2 * i) / 64.0f);
    float f = (float)t * invf;
    cs[idx] = make_float2(cosf(f), sinf(f));
  }
}

// ---------------- bf16 GEMM: C[M][N] = A[M][K] @ Bt[N][K]^T + bias ----------------
// mode 0: write fp32 Cf.  mode 1: RoPE(q,k) fused + scatter bf16 q/k/v as [bh][t][64].
#define BM 128
#define BN 128
#define BKK 32
__global__ __launch_bounds__(256) void gemm_bt(
    const u16* __restrict__ A, const u16* __restrict__ Bt, const float* __restrict__ bias,
    float* __restrict__ Cf, u16* __restrict__ q_ws, u16* __restrict__ k_ws, u16* __restrict__ v_ws,
    const float2* __restrict__ cs, int M, int N, int K, int mode) {
  __shared__ u16 As[BM][BKK];
  __shared__ u16 Bs[BN][BKK];
  const int tid = threadIdx.x;
  const int lane = tid & 63;
  const int wid = tid >> 6;
  const int wr = wid >> 1, wc = wid & 1;
  const int fr = lane & 15, fg = lane >> 4;
  const int m0 = blockIdx.y * BM, n0 = blockIdx.x * BN;

  const int row_l = lane >> 2;
  const int slot_l = lane & 3;

  f32x4 acc[4][4] = {};

  for (int k0 = 0; k0 < K; k0 += BKK) {
#pragma unroll
    for (int i = 0; i < 2; i++) {
      int rowA = wid * 32 + i * 16;
      gld16(A  + (size_t)(m0 + rowA + row_l) * K + k0 + slot_l * 8, &As[rowA][0]);
      gld16(Bt + (size_t)(n0 + rowA + row_l) * K + k0 + slot_l * 8, &Bs[rowA][0]);
    }
    __syncthreads();
    bf16x8 af[4], bfr[4];
#pragma unroll
    for (int i = 0; i < 4; i++)
      af[i] = *reinterpret_cast<const bf16x8*>(&As[wr * 64 + i * 16 + fr][fg * 8]);
#pragma unroll
    for (int j = 0; j < 4; j++)
      bfr[j] = *reinterpret_cast<const bf16x8*>(&Bs[wc * 64 + j * 16 + fr][fg * 8]);
#pragma unroll
    for (int i = 0; i < 4; i++)
#pragma unroll
      for (int j = 0; j < 4; j++)
        acc[i][j] = __builtin_amdgcn_mfma_f32_16x16x32_bf16(af[i], bfr[j], acc[i][j], 0, 0, 0);
    __syncthreads();
  }

  // C/D: col = lane&15, row = (lane>>4)*4 + reg
#pragma unroll
  for (int i = 0; i < 4; i++) {
    int rowb = m0 + wr * 64 + i * 16 + fg * 4;
#pragma unroll
    for (int j = 0; j < 4; j++) {
      int col = n0 + wc * 64 + j * 16 + fr;
      float bv = bias[col];
#pragma unroll
      for (int r = 0; r < 4; r++) {
        float v = acc[i][j][r] + bv;
        int rr = rowb + r;
        if (mode == 0) {
          Cf[(size_t)rr * N + col] = v;
        } else {
          int b = rr >> 11, t = rr & 2047;
          int sec = col >> 10, nn = col & 1023;
          int h = nn >> 6, d = nn & 63;
          float vv = v;
          if (sec < 2) {  // fused RoPE: partner value lives in lane^1 (col^1)
            float vp = __shfl_xor(v, 1);
            float2 c_s = cs[(t << 5) + (d >> 1)];
            vv = (d & 1) ? fmaf(v, c_s.x, vp * c_s.y) : fmaf(v, c_s.x, -vp * c_s.y);
          }
          size_t dst = ((size_t)((b << 4) + h) * 2048 + t) * 64 + d;
          u16 val = f2bf(vv);
          if (sec == 0) q_ws[dst] = val;
          else if (sec == 1) k_ws[dst] = val;
          else v_ws[dst] = val;
        }
      }
    }
  }
}

// ---------------- flash attention, 32 q/wave, swapped-operand dataflow ----------------
#define KVB 64
#define NT 32
#define CSC 0.18033688011112042f   /* log2(e)/8 */
#define THRL2 11.5415603f          /* 8 nats in log2 units (T13 defer-rescale) */

__global__ __launch_bounds__(256, 2) void attn_fwd(const u16* __restrict__ q_ws,
                                                   const u16* __restrict__ k_ws,
                                                   const u16* __restrict__ v_ws,
                                                   u16* __restrict__ attn_out) {
  __shared__ u16 Klds[2][4096];  // byte(row,d) = row*128 + (d*2  ^ ((row&7)<<4))
  __shared__ u16 Vlds[2][4096];  // byte(d,key) = d*128   + (key*2 ^ ((d&7)<<4))

  const int tid = threadIdx.x, lane = tid & 63, w = tid >> 6;
  const int l31 = lane & 31, hi = lane >> 5;
  // XCD swizzle: 512 blocks = 8 x 64; chunk of 64 consecutive work-ids per XCD (4 bh each)
  const int bid = blockIdx.x;
  const int wrk = (bid & 7) * 64 + (bid >> 3);
  const int bh = wrk >> 4;
  const int q0 = (wrk & 15) * 128 + w * 32;
  const size_t base = (size_t)bh * (2048 * 64);

  bf16x8 qf[4];
#pragma unroll
  for (int db = 0; db < 4; db++)
    qf[db] = *reinterpret_cast<const bf16x8*>(
        q_ws + base + (size_t)(q0 + l31) * 64 + db * 16 + hi * 8);

  f32x16 Oa[2] = {};             // O^T: col=q(lane&31), row=d (16 regs per 32-d half)
  float m_i = -1e30f, l_i = 0.f;

  const int krow_l = lane >> 3, kslot_l = lane & 7;
  const int vkey = tid & 31, vc = tid >> 5;
  const u16* kg = k_ws + base;
  const u16* vg = v_ws + base;

#define STAGE_K(kv, buf)                                                          \
  {                                                                               \
    _Pragma("unroll") for (int i = 0; i < 2; i++) {                               \
      int row = w * 16 + i * 8 + krow_l;                                          \
      int srcslot = kslot_l ^ (row & 7);                                          \
      gld16(kg + (size_t)((kv) + row) * 64 + srcslot * 8, &Klds[buf][(w * 16 + i * 8) * 64]); \
    }                                                                             \
  }
#define LOAD_V(kv, vrg)                                                           \
  {                                                                               \
    vrg[0] = *reinterpret_cast<const uint4*>(vg + (size_t)((kv) + vkey) * 64 + vc * 8);       \
    vrg[1] = *reinterpret_cast<const uint4*>(vg + (size_t)((kv) + vkey + 32) * 64 + vc * 8);  \
  }
#define SCATTER_V(vrg, buf)                                                       \
  {                                                                               \
    _Pragma("unroll") for (int it = 0; it < 2; it++) {                            \
      const u16* pe = (const u16*)&vrg[it];                                       \
      int key2 = (vkey + 32 * it) * 2;                                            \
      _Pragma("unroll") for (int j = 0; j < 8; j++) {                             \
        int byte = (vc * 8 + j) * 128 + (key2 ^ (j << 4));                        \
        *(u16*)((char*)&Vlds[buf][0] + byte) = pe[j];                             \
      }                                                                           \
    }                                                                             \
  }

  uint4 vr[2];
  STAGE_K(0, 0);
  LOAD_V(0, vr);
  __syncthreads();
  SCATTER_V(vr, 0);
  __syncthreads();

  int cur = 0;
  for (int t = 0; t < NT; t++) {
    if (t + 1 < NT) {
      STAGE_K((t + 1) * KVB, cur ^ 1);
      LOAD_V((t + 1) * KVB, vr);
    }

    const char* Kb = (const char*)&Klds[cur][0];
    const char* Vb = (const char*)&Vlds[cur][0];

    bf16x8 kf[2][4];
#pragma unroll
    for (int ks = 0; ks < 2; ks++) {
      int krow = (l31 + 32 * ks) * 128;
      int ksw = (l31 & 7) << 4;
#pragma unroll
      for (int db = 0; db < 4; db++)
        kf[ks][db] = *reinterpret_cast<const bf16x8*>(Kb + krow + ((db * 32 + hi * 16) ^ ksw));
    }

    f32x16 s0 = {}, s1 = {};
    __builtin_amdgcn_s_setprio(1);
#pragma unroll
    for (int db = 0; db < 4; db++) {
      s0 = __builtin_amdgcn_mfma_f32_32x32x16_bf16(kf[0][db], qf[db], s0, 0, 0, 0);
      s1 = __builtin_amdgcn_mfma_f32_32x32x16_bf16(kf[1][db], qf[db], s1, 0, 0, 0);
    }
    __builtin_amdgcn_s_setprio(0);

    // ---- row max (balanced tree on raw scores, scale once) ----
    float a[8];
#pragma unroll
    for (int i = 0; i < 8; i++)
      a[i] = fmaxf(fmaxf(s0[i], s0[i + 8]), fmaxf(s1[i], s1[i + 8]));
    a[0] = fmaxf(a[0], a[4]); a[1] = fmaxf(a[1], a[5]);
    a[2] = fmaxf(a[2], a[6]); a[3] = fmaxf(a[3], a[7]);
    float zx = fmaxf(fmaxf(a[0], a[1]), fmaxf(a[2], a[3])) * CSC;
    zx = fmaxf(zx, __shfl_xor(zx, 32));

    // T13 defer-rescale: only rescale when row-max grew past threshold
    if (__any(zx > m_i + THRL2)) {
      float mn = fmaxf(m_i, zx);
      float alpha = exp2f(m_i - mn);
      m_i = mn;
      l_i *= alpha;
#pragma unroll
      for (int ds = 0; ds < 2; ds++)
#pragma unroll
        for (int r = 0; r < 16; r++) Oa[ds][r] *= alpha;
    }

    float p[32];
#pragma unroll
    for (int i = 0; i < 16; i++) {
      p[i]      = exp2f(fmaf(s0[i], CSC, -m_i));
      p[16 + i] = exp2f(fmaf(s1[i], CSC, -m_i));
    }
    float r0 = 0.f, r1 = 0.f, r2 = 0.f, r3 = 0.f;
#pragma unroll
    for (int i = 0; i < 8; i++) {
      r0 += p[i]; r1 += p[i + 8]; r2 += p[i + 16]; r3 += p[i + 24];
    }
    float rs = (r0 + r1) + (r2 + r3);
    rs += __shfl_xor(rs, 32);
    l_i += rs;

    // pack P -> bf16 pairs (manual RNE pack; compiler schedules the shifts fine)
    u32 pw[16];
#pragma unroll
    for (int kk = 0; kk < 2; kk++)
#pragma unroll
      for (int wd = 0; wd < 8; wd++)
        pw[kk * 8 + wd] =
            ((u32)f2bf(p[kk * 16 + 2 * wd + 1]) << 16) | (u32)f2bf(p[kk * 16 + 2 * wd]);

    // ---- PV: O^T += V^T @ P^T ----
    int vsw = (l31 & 7) << 4;
    __builtin_amdgcn_s_setprio(1);
#pragma unroll
    for (int ds = 0; ds < 2; ds++) {
      int vrow = (l31 + 32 * ds) * 128;
#pragma unroll
      for (int kb = 0; kb < 4; kb++) {
        uint2 va = *(const uint2*)(Vb + vrow + ((kb * 32 + hi * 8) ^ vsw));
        uint2 vb2 = *(const uint2*)(Vb + vrow + ((kb * 32 + hi * 8 + 16) ^ vsw));
        union { u32 u[4]; bf16x8 v; } vf, pf;
        vf.u[0] = va.x; vf.u[1] = va.y; vf.u[2] = vb2.x; vf.u[3] = vb2.y;
        int pb = (kb >> 1) * 8 + (kb & 1) * 4;
        pf.u[0] = pw[pb]; pf.u[1] = pw[pb + 1]; pf.u[2] = pw[pb + 2]; pf.u[3] = pw[pb + 3];
        Oa[ds] = __builtin_amdgcn_mfma_f32_32x32x16_bf16(vf.v, pf.v, Oa[ds], 0, 0, 0);
      }
    }
    __builtin_amdgcn_s_setprio(0);

    if (t + 1 < NT) SCATTER_V(vr, cur ^ 1);
    __syncthreads();   // drains gld_lds; orders scatter/stage vs next-iter reads (WAR safe)
    cur ^= 1;
  }

  // ---- epilogue ----
  const int b = bh >> 4, h = bh & 15;
  float invl = 1.0f / l_i;
  int row = q0 + l31;
  size_t rbase = ((size_t)(b * 2048 + row)) * 1024 + h * 64;
#pragma unroll
  for (int ds = 0; ds < 2; ds++)
#pragma unroll
    for (int rg = 0; rg < 4; rg++) {
      int d0 = rg * 8 + hi * 4 + ds * 32;
      ushort4 st;
      st.x = f2bf(Oa[ds][rg * 4 + 0] * invl);
      st.y = f2bf(Oa[ds][rg * 4 + 1] * invl);
      st.z = f2bf(Oa[ds][rg * 4 + 2] * invl);
      st.w = f2bf(Oa[ds][rg * 4 + 3] * invl);
      *reinterpret_cast<ushort4*>(attn_out + rbase + d0) = st;
    }
#undef STAGE_K
#undef LOAD_V
#undef SCATTER_V
}

extern "C" void kernel_launch(void* const* d_in, const int* in_sizes, int n_in,
                              void* d_out, int out_size, void* d_ws, size_t ws_size,
                              hipStream_t stream) {
  const float* x     = (const float*)d_in[0];  // [2][2048][1024]
  const float* w_qkv = (const float*)d_in[1];  // [1024][3072]
  const float* b_qkv = (const float*)d_in[2];  // [3072]
  const float* w_out = (const float*)d_in[3];  // [1024][1024]
  const float* b_out = (const float*)d_in[4];  // [1024]
  float* out = (float*)d_out;                  // [2][2048][1024] fp32

  char* ws = (char*)d_ws;
  const size_t MB = 1024 * 1024;
  u16*    x_bf   = (u16*)(ws);                 // 8 MB  [4096][1024]
  u16*    wqkvT  = (u16*)(ws + 8 * MB);        // 6 MB  [3072][1024]
  u16*    woutT  = (u16*)(ws + 14 * MB);       // 2 MB  [1024][1024]
  u16*    q_ws   = (u16*)(ws + 16 * MB);       // 8 MB  [2][16][2048][64]
  u16*    k_ws   = (u16*)(ws + 24 * MB);       // 8 MB
  u16*    v_ws   = (u16*)(ws + 32 * MB);       // 8 MB
  u16*    attn_o = (u16*)(ws + 40 * MB);       // 8 MB  [4096][1024]
  float2* cs     = (float2*)(ws + 48 * MB);    // 512 KB [2048][32] (cos,sin)

  prep<<<8448, 256, 0, stream>>>(x, x_bf, w_qkv, wqkvT, w_out, woutT, cs);
  gemm_bt<<<dim3(24, 32), 256, 0, stream>>>(x_bf, wqkvT, b_qkv, nullptr, q_ws, k_ws, v_ws,
                                            cs, 4096, 3072, 1024, 1);
  attn_fwd<<<512, 256, 0, stream>>>(q_ws, k_ws, v_ws, attn_o);
  gemm_bt<<<dim3(8, 32), 256, 0, stream>>>(attn_o, woutT, b_out, out, nullptr, nullptr, nullptr,
                                           nullptr, 4096, 1024, 1024, 0);
}